// Round 1
// baseline (39971.646 us; speedup 1.0000x reference)
//
#include <hip/hip_runtime.h>

// Bidirectional LSTM, L=512, B=64, E=H=512, fp32.
// One cooperative persistent kernel: 256 blocks (128 fwd, 128 bwd), 256 thr.
// Block owns 4 h-columns -> 16 weight rows (Wih+Whh) resident in LDS (136.5KB).
// Per step: stage x (emb gather, masked) + broadcast h into LDS chunk-wise with
// register prefetch one chunk ahead; custom slot-based grid barrier (agent-scope
// release/acquire) between steps; c lives in registers for all 512 steps.

#define LL 512
#define BB 64
#define HH 512
#define EE 512
#define NBLK 256
#define NTHR 256

struct Params {
  const int* tokens; const float* mask; const float* emb;
  const float* WihF; const float* WhhF; const float* bihF; const float* bhhF;
  const float* WihB; const float* WhhB; const float* bihB; const float* bhhB;
  float* out; float* hT; int* bar; const float* zpage;
};

__device__ __forceinline__ float sigf(float x)   { return 1.0f / (1.0f + __expf(-x)); }
// NaN-free tanh (saturates cleanly at +/-1 for large |x|)
__device__ __forceinline__ float tanhf2(float x) { return 2.0f / (1.0f + __expf(-2.0f * x)) - 1.0f; }

__launch_bounds__(NTHR, 1)
__global__ void lstm_coop(Params p) {
  __shared__ float wih_s[16 * 512];   // [r=jj*4+g][k]   32.0 KB
  __shared__ float whh_s[16 * 516];   // padded rows     33.0 KB (distinct bank quads for 4 gate rows)
  __shared__ float x_s[64 * 132];     // [b][k] chunk    33.0 KB (stride 132 -> m134-pattern b128 reads)
  __shared__ float h_s[128 * 68];     // [k][b] chunk    34.0 KB
  __shared__ float gmat[16 * 68];     // per-wave gate transpose
  __shared__ float hout[4 * 64];      // h staging for coalesced out-write

  const int tid  = threadIdx.x;
  const int blk  = blockIdx.x;
  const int dir  = blk >> 7;            // 0=fwd, 1=bwd
  const int j0   = (blk & 127) << 2;    // 4 owned h-columns
  const int lane = tid & 63;
  const int wv   = tid >> 6;            // wave id = jj (column offset)

  const float* __restrict__ Wih = dir ? p.WihB : p.WihF;
  const float* __restrict__ Whh = dir ? p.WhhB : p.WhhF;
  const float* bih = dir ? p.bihB : p.bihF;
  const float* bhh = dir ? p.bhhB : p.bhhF;

  // Resident weights -> LDS. LDS row r = jj*4 + g, global row = g*H + j0 + jj.
  for (int idx = tid; idx < 16 * 512; idx += NTHR) {
    int r = idx >> 9, k = idx & 511;
    int g = r & 3, jj = r >> 2;
    int grow = g * HH + j0 + jj;
    wih_s[r * 512 + k] = Wih[grow * EE + k];
    whh_s[r * 516 + k] = Whh[grow * HH + k];
  }
  float biasg[4];
  #pragma unroll
  for (int g = 0; g < 4; ++g) {
    int grow = g * HH + j0 + wv;
    biasg[g] = bih[grow] + bhh[grow];
  }

  float c_reg = 0.0f;                               // c[b=lane][j0+wv], resident all steps
  float* hT0  = p.hT + (size_t)dir * (2 * HH * BB); // [buf][j][b] double buffer
  int* slots  = p.bar;                              // 256 arrival slots
  int* genp   = p.bar + 320;                        // generation flag (separate line)

  __syncthreads();

  float4 pf[8];  // register prefetch (one 32KB chunk ahead)

  // Prologue: prefetch x chunk 0 of step 0
  {
    int t0 = dir ? (LL - 1) : 0;
    #pragma unroll
    for (int it = 0; it < 8; ++it) {
      int lin = (tid << 2) + (it << 10);
      int b = lin >> 7, kq = lin & 127;
      int tok = p.tokens[t0 * BB + b];
      const float* src = (tok >= 0) ? (p.emb + (size_t)tok * EE + kq) : (p.zpage + kq);
      pf[it] = *(const float4*)src;
    }
  }

  #pragma unroll 1
  for (int s = 0; s < LL; ++s) {
    const int t = dir ? (LL - 1 - s) : s;
    const float* hprev = hT0 + (size_t)(s & 1) * (HH * BB);
    float accx[4] = {0.f, 0.f, 0.f, 0.f};

    // ---------------- PHASE X: x @ Wih^T (4 chunks of K=128) ----------------
    #pragma unroll 1
    for (int c = 0; c < 4; ++c) {
      #pragma unroll
      for (int it = 0; it < 8; ++it) {           // regs -> LDS
        int lin = (tid << 2) + (it << 10);
        int b = lin >> 7, kq = lin & 127;
        *(float4*)&x_s[b * 132 + kq] = pf[it];
      }
      __syncthreads();
      if (c < 3) {                                // prefetch next x chunk
        #pragma unroll
        for (int it = 0; it < 8; ++it) {
          int lin = (tid << 2) + (it << 10);
          int b = lin >> 7, kq = lin & 127;
          int tok = p.tokens[t * BB + b];
          const float* src = (tok >= 0) ? (p.emb + (size_t)tok * EE + (c + 1) * 128 + kq)
                                        : (p.zpage + kq);
          pf[it] = *(const float4*)src;
        }
      } else {                                    // prefetch h chunk 0 (post-barrier: safe)
        #pragma unroll
        for (int it = 0; it < 8; ++it) {
          int lin = (tid << 2) + (it << 10);
          pf[it] = *(const float4*)&hprev[lin];
        }
      }
      // mapping A: lane=b, wave=jj, accumulate 4 gates
      const float* xrow = &x_s[lane * 132];
      const int kbase = c * 128;
      #pragma unroll 8
      for (int kq = 0; kq < 128; kq += 4) {
        float4 xv = *(const float4*)&xrow[kq];
        #pragma unroll
        for (int g = 0; g < 4; ++g) {
          float4 wvv = *(const float4*)&wih_s[((wv * 4 + g) << 9) + kbase + kq];
          accx[g] += wvv.x * xv.x + wvv.y * xv.y + wvv.z * xv.z + wvv.w * xv.w;
        }
      }
      __syncthreads();
    }

    // ---------------- PHASE H: h @ Whh^T (4 chunks of K=128) ----------------
    float acch[4] = {0.f, 0.f, 0.f, 0.f};
    const int gH = lane >> 4, bg = lane & 15;     // mapping B: lane=(gate, b-group)
    #pragma unroll 1
    for (int c = 0; c < 4; ++c) {
      #pragma unroll
      for (int it = 0; it < 8; ++it) {            // regs -> LDS ([k][b], straight copy)
        int lin = (tid << 2) + (it << 10);
        int k = lin >> 6, bq = lin & 63;
        *(float4*)&h_s[k * 68 + bq] = pf[it];
      }
      __syncthreads();
      if (c < 3) {
        #pragma unroll
        for (int it = 0; it < 8; ++it) {
          int lin = (tid << 2) + (it << 10);
          pf[it] = *(const float4*)&hprev[(c + 1) * 8192 + lin];
        }
      } else if (s + 1 < LL) {                    // cross-barrier x prefetch for step s+1
        int tn = dir ? (LL - 2 - s) : (s + 1);
        #pragma unroll
        for (int it = 0; it < 8; ++it) {
          int lin = (tid << 2) + (it << 10);
          int b = lin >> 7, kq = lin & 127;
          int tok = p.tokens[tn * BB + b];
          const float* src = (tok >= 0) ? (p.emb + (size_t)tok * EE + kq) : (p.zpage + kq);
          pf[it] = *(const float4*)src;
        }
      }
      const float* wrow = &whh_s[(wv * 4 + gH) * 516 + c * 128];
      #pragma unroll 8
      for (int k0 = 0; k0 < 128; k0 += 4) {
        float4 wvv = *(const float4*)&wrow[k0];
        float4 h0 = *(const float4*)&h_s[(k0 + 0) * 68 + (bg << 2)];
        float4 h1 = *(const float4*)&h_s[(k0 + 1) * 68 + (bg << 2)];
        float4 h2 = *(const float4*)&h_s[(k0 + 2) * 68 + (bg << 2)];
        float4 h3 = *(const float4*)&h_s[(k0 + 3) * 68 + (bg << 2)];
        acch[0] += wvv.x * h0.x + wvv.y * h1.x + wvv.z * h2.x + wvv.w * h3.x;
        acch[1] += wvv.x * h0.y + wvv.y * h1.y + wvv.z * h2.y + wvv.w * h3.y;
        acch[2] += wvv.x * h0.z + wvv.y * h1.z + wvv.z * h2.z + wvv.w * h3.z;
        acch[3] += wvv.x * h0.w + wvv.y * h1.w + wvv.z * h2.w + wvv.w * h3.w;
      }
      __syncthreads();
    }

    // Transpose acch (mapping B) into per-lane-b layout via LDS, combine, gates.
    *(float4*)&gmat[(wv * 4 + gH) * 68 + (bg << 2)] = make_float4(acch[0], acch[1], acch[2], acch[3]);
    __syncthreads();

    float gate[4];
    #pragma unroll
    for (int g = 0; g < 4; ++g)
      gate[g] = accx[g] + gmat[(wv * 4 + g) * 68 + lane] + biasg[g];

    float ig = sigf(gate[0]);
    float fg = sigf(gate[1]);
    float gg = tanhf2(gate[2]);
    float og = sigf(gate[3]);
    float m  = p.mask[t * BB + lane];
    float cu = fg * c_reg + ig * gg;
    float hu = og * tanhf2(cu);
    c_reg = cu * m;
    float hn = hu * m;

    float* hnext = hT0 + (size_t)((s & 1) ^ 1) * (HH * BB);
    hnext[(j0 + wv) * BB + lane] = hn;    // [j][b], coalesced 256B per wave
    hout[wv * 64 + lane] = hn;

    // -------- grid barrier: parallel slot arrivals, block0 aggregates --------
    __threadfence();
    __syncthreads();
    if (blk == 0) {
      if (tid == 0)
        __hip_atomic_store(&slots[0], s + 1, __ATOMIC_RELEASE, __HIP_MEMORY_SCOPE_AGENT);
      for (;;) {
        int ok = (__hip_atomic_load(&slots[tid], __ATOMIC_ACQUIRE, __HIP_MEMORY_SCOPE_AGENT) >= s + 1);
        if (__syncthreads_and(ok)) break;
        __builtin_amdgcn_s_sleep(1);
      }
      if (tid == 0)
        __hip_atomic_store(genp, s + 1, __ATOMIC_RELEASE, __HIP_MEMORY_SCOPE_AGENT);
    } else {
      if (tid == 0) {
        __hip_atomic_store(&slots[blk], s + 1, __ATOMIC_RELEASE, __HIP_MEMORY_SCOPE_AGENT);
        while (__hip_atomic_load(genp, __ATOMIC_ACQUIRE, __HIP_MEMORY_SCOPE_AGENT) < s + 1)
          __builtin_amdgcn_s_sleep(1);
      }
      __syncthreads();
    }

    // Coalesced float4 output write (overlaps next step's staging)
    if (wv == 0) {
      float4 o4 = make_float4(hout[lane], hout[64 + lane], hout[128 + lane], hout[192 + lane]);
      *(float4*)&p.out[((size_t)(t * BB + lane)) * (2 * HH) + dir * HH + j0] = o4;
    }
  }
}

extern "C" void kernel_launch(void* const* d_in, const int* in_sizes, int n_in,
                              void* d_out, int out_size, void* d_ws, size_t ws_size,
                              hipStream_t stream) {
  (void)in_sizes; (void)n_in; (void)out_size; (void)ws_size;
  Params prm;
  prm.tokens = (const int*)d_in[0];
  prm.mask   = (const float*)d_in[1];
  prm.emb    = (const float*)d_in[2];
  prm.WihF   = (const float*)d_in[3];
  prm.WhhF   = (const float*)d_in[4];
  prm.bihF   = (const float*)d_in[5];
  prm.bhhF   = (const float*)d_in[6];
  prm.WihB   = (const float*)d_in[7];
  prm.WhhB   = (const float*)d_in[8];
  prm.bihB   = (const float*)d_in[9];
  prm.bihB   = (const float*)d_in[9];
  prm.bhhB   = (const float*)d_in[10];
  prm.out    = (float*)d_out;
  // ws layout: [0,512K) h double buffers (2 dir x 2 buf x 512 x 64 f32)
  //            [512K, 512K+4K) barrier slots + gen
  //            [516K, 520K) zeros page for masked-token gather
  prm.hT     = (float*)d_ws;
  prm.bar    = (int*)((char*)d_ws + 524288);
  prm.zpage  = (const float*)((char*)d_ws + 528384);

  hipMemsetAsync(d_ws, 0, 532480, stream);  // zero h bufs + barrier + zpage

  void* args[] = {(void*)&prm};
  hipLaunchCooperativeKernel((const void*)lstm_coop, dim3(NBLK), dim3(NTHR), args, 0, stream);
}

// Round 2
// 30285.345 us; speedup vs baseline: 1.3198x; 1.3198x over previous
//
#include <hip/hip_runtime.h>

// Bidirectional LSTM L=512, B=64, E=H=512 fp32 — MFMA split-bf16 persistent kernel.
// 256 blocks x 512 thr (8 waves). Block owns 4 h-units = 16 gate-rows = one
// MFMA M-tile. Weights preloaded ONCE into registers as bf16 hi/lo A-fragments
// (128 VGPR/wave) -> no weight traffic in the loop. z=[x;h] staged in LDS as
// bf16 hi/lo; 3-product split MFMA (hi*hi + hi*lo + lo*hi) gives ~fp32 error.
// Two independent 128-block barrier groups (fwd/bwd); arrive-early/wait-late
// so x-staging + X-phase MFMA overlap barrier latency.

#define LL 512
#define BB 64
#define HH 512
#define NBLK 256
#define NTHR 512

typedef __attribute__((ext_vector_type(8))) __bf16 bf16x8;
typedef __attribute__((ext_vector_type(4))) __bf16 bf16x4;
typedef __attribute__((ext_vector_type(4))) float f32x4;

struct Params {
  const int* tokens; const float* mask; const float* emb;
  const float* WihF; const float* WhhF; const float* bihF; const float* bhhF;
  const float* WihB; const float* WhhB; const float* bihB; const float* bhhB;
  float* out; float* hT; int* bar;
};

__device__ __forceinline__ float sigf(float x)  { return 1.0f / (1.0f + __expf(-x)); }
__device__ __forceinline__ float tanh2(float x) { return 2.0f / (1.0f + __expf(-2.0f * x)) - 1.0f; }

__launch_bounds__(NTHR, 2)
__global__ void lstm_mfma(Params p) {
  __shared__ __bf16 zhi[64 * 520];   // [b][k] bf16, pad 520 (65 f4 -> conflict-free)
  __shared__ __bf16 zlo[64 * 520];
  __shared__ f32x4  red[8 * 64];     // k-half reduce exchange
  __shared__ float  hsh[4 * 64];     // [jj][b] h gather for coalesced writes

  const int tid   = threadIdx.x;
  const int blk   = blockIdx.x;
  const int dir   = blk >> 7;           // 0=fwd 1=bwd
  const int j0    = (blk & 127) << 2;   // 4 owned h-units
  const int lane  = tid & 63;
  const int wv    = tid >> 6;           // 8 waves
  const int khalf = wv >> 2;            // K-half split across wave pairs
  const int ntile = wv & 3;             // 4 N-tiles of 16 batch cols
  const int quad  = lane >> 4;
  const int mrow  = lane & 15;
  const int col   = ntile * 16 + mrow;  // batch column this lane owns in C

  const float* __restrict__ Wih = dir ? p.WihB : p.WihF;
  const float* __restrict__ Whh = dir ? p.WhhB : p.WhhF;
  const float* bih = dir ? p.bihB : p.bihF;
  const float* bhh = dir ? p.bhhB : p.bhhF;

  // ---- one-time: preload A-fragments (weights) into registers, split hi/lo ----
  // MFMA A layout: A[m=lane&15][k=quad*8+j]. Row m -> gate g=m&3, unit jj=m>>2
  // => C lane (col b) regs 0..3 = the 4 gates of unit quad. No transpose needed.
  bf16x8 aXhi[8], aXlo[8], aHhi[8], aHlo[8];
  const int grow = (mrow & 3) * HH + j0 + (mrow >> 2);
  #pragma unroll
  for (int s8 = 0; s8 < 8; ++s8) {
    const int kb = khalf * 256 + s8 * 32 + quad * 8;
    const float* wp = Wih + (size_t)grow * HH + kb;
    const float* wq = Whh + (size_t)grow * HH + kb;
    #pragma unroll
    for (int j = 0; j < 8; ++j) {
      float v = wp[j];
      __bf16 h = (__bf16)v;
      aXhi[s8][j] = h; aXlo[s8][j] = (__bf16)(v - (float)h);
      float u = wq[j];
      __bf16 g = (__bf16)u;
      aHhi[s8][j] = g; aHlo[s8][j] = (__bf16)(u - (float)g);
    }
  }
  float bias4[4];
  #pragma unroll
  for (int g = 0; g < 4; ++g)
    bias4[g] = bih[g * HH + j0 + quad] + bhh[g * HH + j0 + quad];  // unit jj=quad (waves<4)

  float c_reg = 0.0f;
  float* hT0 = p.hT + (size_t)dir * (2 * HH * BB);  // [buf][b][j] fp32
  int* slots = p.bar;                                // 256 arrival slots
  const int gb = dir * 128;
  int* gen = p.bar + 512 + dir * 32;                 // per-group generation flag
  const int leader = ((blk & 127) == 0);

  __syncthreads();

  #pragma unroll 1
  for (int s = 0; s < LL; ++s) {
    const int t = dir ? (LL - 1 - s) : s;
    f32x4 acc = {0.f, 0.f, 0.f, 0.f};

    // ---------- stage x(t): emb gather -> bf16 hi/lo in LDS ----------
    #pragma unroll 4
    for (int it = 0; it < 16; ++it) {
      int lin = (tid << 2) + (it << 11);
      int b = lin >> 9, k = lin & 511;
      int tok = p.tokens[t * BB + b];
      float4 v = make_float4(0.f, 0.f, 0.f, 0.f);
      if (tok >= 0) v = *(const float4*)(p.emb + (size_t)tok * HH + k);
      bf16x4 h4, l4;
      h4[0] = (__bf16)v.x; l4[0] = (__bf16)(v.x - (float)h4[0]);
      h4[1] = (__bf16)v.y; l4[1] = (__bf16)(v.y - (float)h4[1]);
      h4[2] = (__bf16)v.z; l4[2] = (__bf16)(v.z - (float)h4[2]);
      h4[3] = (__bf16)v.w; l4[3] = (__bf16)(v.w - (float)h4[3]);
      *(bf16x4*)&zhi[b * 520 + k] = h4;
      *(bf16x4*)&zlo[b * 520 + k] = l4;
    }
    __syncthreads();

    // ---------- MFMA phase X (overlaps barrier wait below) ----------
    #pragma unroll
    for (int s8 = 0; s8 < 8; ++s8) {
      const int kk = khalf * 256 + s8 * 32 + quad * 8;
      bf16x8 bh = *(const bf16x8*)&zhi[col * 520 + kk];
      bf16x8 bl = *(const bf16x8*)&zlo[col * 520 + kk];
      acc = __builtin_amdgcn_mfma_f32_16x16x32_bf16(aXhi[s8], bh, acc, 0, 0, 0);
      acc = __builtin_amdgcn_mfma_f32_16x16x32_bf16(aXhi[s8], bl, acc, 0, 0, 0);
      acc = __builtin_amdgcn_mfma_f32_16x16x32_bf16(aXlo[s8], bh, acc, 0, 0, 0);
    }

    // ---------- wait-late barrier: h(s-1) ready ----------
    if (s) {
      if (leader) {
        if (tid < 128) {
          while (__hip_atomic_load(&slots[gb + tid], __ATOMIC_ACQUIRE, __HIP_MEMORY_SCOPE_AGENT) < s)
            __builtin_amdgcn_s_sleep(1);
        }
        __syncthreads();
        if (tid == 0)
          __hip_atomic_store(gen, s, __ATOMIC_RELEASE, __HIP_MEMORY_SCOPE_AGENT);
      } else {
        if (tid == 0) {
          while (__hip_atomic_load(gen, __ATOMIC_ACQUIRE, __HIP_MEMORY_SCOPE_AGENT) < s)
            __builtin_amdgcn_s_sleep(1);
        }
        __syncthreads();
      }
    } else {
      __syncthreads();
    }

    // ---------- stage h(s-1) -> bf16 hi/lo in LDS ----------
    const float* hb = hT0 + (size_t)(s & 1) * (HH * BB);
    #pragma unroll 4
    for (int it = 0; it < 16; ++it) {
      int lin = (tid << 2) + (it << 11);
      int b = lin >> 9, k = lin & 511;
      float4 v = *(const float4*)(hb + b * 512 + k);
      bf16x4 h4, l4;
      h4[0] = (__bf16)v.x; l4[0] = (__bf16)(v.x - (float)h4[0]);
      h4[1] = (__bf16)v.y; l4[1] = (__bf16)(v.y - (float)h4[1]);
      h4[2] = (__bf16)v.z; l4[2] = (__bf16)(v.z - (float)h4[2]);
      h4[3] = (__bf16)v.w; l4[3] = (__bf16)(v.w - (float)h4[3]);
      *(bf16x4*)&zhi[b * 520 + k] = h4;
      *(bf16x4*)&zlo[b * 520 + k] = l4;
    }
    __syncthreads();

    // ---------- MFMA phase H ----------
    #pragma unroll
    for (int s8 = 0; s8 < 8; ++s8) {
      const int kk = khalf * 256 + s8 * 32 + quad * 8;
      bf16x8 bh = *(const bf16x8*)&zhi[col * 520 + kk];
      bf16x8 bl = *(const bf16x8*)&zlo[col * 520 + kk];
      acc = __builtin_amdgcn_mfma_f32_16x16x32_bf16(aHhi[s8], bh, acc, 0, 0, 0);
      acc = __builtin_amdgcn_mfma_f32_16x16x32_bf16(aHhi[s8], bl, acc, 0, 0, 0);
      acc = __builtin_amdgcn_mfma_f32_16x16x32_bf16(aHlo[s8], bh, acc, 0, 0, 0);
    }

    // ---------- k-half reduce + gates (all in-lane) ----------
    red[wv * 64 + lane] = acc;
    __syncthreads();
    if (wv < 4) {
      f32x4 o = red[(wv + 4) * 64 + lane];
      float g0 = acc[0] + o[0] + bias4[0];
      float g1 = acc[1] + o[1] + bias4[1];
      float g2 = acc[2] + o[2] + bias4[2];
      float g3 = acc[3] + o[3] + bias4[3];
      float ig = sigf(g0), fg = sigf(g1), gg = tanh2(g2), og = sigf(g3);
      float m  = p.mask[t * BB + col];
      float cu = fg * c_reg + ig * gg;
      float hu = og * tanh2(cu);
      c_reg = cu * m;
      hsh[quad * 64 + col] = hu * m;
    }
    __syncthreads();
    if (wv == 0) {  // coalesced float4 writes of the block's 4 h-units
      float4 o4 = make_float4(hsh[lane], hsh[64 + lane], hsh[128 + lane], hsh[192 + lane]);
      float* hnext = hT0 + (size_t)((s & 1) ^ 1) * (HH * BB);
      *(float4*)(hnext + lane * 512 + j0) = o4;
      *(float4*)(p.out + ((size_t)(t * BB + lane)) * (2 * HH) + dir * HH + j0) = o4;
    }

    // ---------- arrive-early ----------
    __threadfence();
    __syncthreads();
    if (tid == 0)
      __hip_atomic_store(&slots[gb + (blk & 127)], s + 1, __ATOMIC_RELEASE, __HIP_MEMORY_SCOPE_AGENT);
  }
}

extern "C" void kernel_launch(void* const* d_in, const int* in_sizes, int n_in,
                              void* d_out, int out_size, void* d_ws, size_t ws_size,
                              hipStream_t stream) {
  (void)in_sizes; (void)n_in; (void)out_size; (void)ws_size;
  Params prm;
  prm.tokens = (const int*)d_in[0];
  prm.mask   = (const float*)d_in[1];
  prm.emb    = (const float*)d_in[2];
  prm.WihF   = (const float*)d_in[3];
  prm.WhhF   = (const float*)d_in[4];
  prm.bihF   = (const float*)d_in[5];
  prm.bhhF   = (const float*)d_in[6];
  prm.WihB   = (const float*)d_in[7];
  prm.WhhB   = (const float*)d_in[8];
  prm.bihB   = (const float*)d_in[9];
  prm.bhhB   = (const float*)d_in[10];
  prm.out    = (float*)d_out;
  // ws: [0,512K) h double buffers [dir][buf][b][j] fp32; [512K,516K) barrier
  prm.hT  = (float*)d_ws;
  prm.bar = (int*)((char*)d_ws + 524288);

  hipMemsetAsync(d_ws, 0, 528384, stream);

  void* args[] = {(void*)&prm};
  hipLaunchCooperativeKernel((const void*)lstm_mfma, dim3(NBLK), dim3(NTHR), args, 0, stream);
}

// Round 3
// 8515.073 us; speedup vs baseline: 4.6942x; 3.5567x over previous
//
#include <hip/hip_runtime.h>

// Bidirectional LSTM L=512, B=64, E=H=512 fp32 — MFMA split-bf16 persistent kernel.
// Round 3: NO agent release/acquire fences (they emit buffer_wbl2/buffer_inv =
// per-step L2 writeback+invalidate across all 256 blocks; ~60us/step stall in
// rounds 1-2). All cross-block exchange (h state + barrier slots) goes through
// RELAXED agent-scope atomics (sc0/sc1 path straight to the L3 coherence point,
// no cache maintenance). Ordering: wave-local `s_waitcnt vmcnt(0)` between h
// stores and the slot store; L3 is the single serialization point.
// h is exchanged pre-split as bf16 (hi,lo) packed in 4B/element (exactly what
// the MFMA consumes) — half the traffic, no cvt on the read side.

#define LL 512
#define BB 64
#define HH 512
#define NBLK 256
#define NTHR 512

typedef __attribute__((ext_vector_type(8))) __bf16 bf16x8;
typedef __attribute__((ext_vector_type(4))) float f32x4;
typedef unsigned int u32;
typedef unsigned long long u64;
typedef unsigned short u16;

struct Params {
  const int* tokens; const float* mask; const float* emb;
  const float* WihF; const float* WhhF; const float* bihF; const float* bhhF;
  const float* WihB; const float* WhhB; const float* bihB; const float* bhhB;
  float* out; u32* hx; int* bar;
};

__device__ __forceinline__ float sigf(float x)  { return 1.0f / (1.0f + __expf(-x)); }
__device__ __forceinline__ float tanh2(float x) { return 2.0f / (1.0f + __expf(-2.0f * x)) - 1.0f; }

__device__ __forceinline__ void split1(float v, u16& hi, u16& lo) {
  __bf16 h = (__bf16)v;
  __bf16 l = (__bf16)(v - (float)h);
  hi = __builtin_bit_cast(u16, h);
  lo = __builtin_bit_cast(u16, l);
}

__launch_bounds__(NTHR, 1)
__global__ void lstm_mfma(Params p) {
  __shared__ u16   zhi[64 * 520];    // [b][k] bf16-hi bits, pad 520
  __shared__ u16   zlo[64 * 520];    // bf16-lo bits
  __shared__ f32x4 red[8 * 64];      // k-half reduce exchange
  __shared__ float hsh[4 * 64];      // [jj][b] h gather

  const int tid   = threadIdx.x;
  const int blk   = blockIdx.x;
  const int dir   = blk >> 7;           // 0=fwd 1=bwd
  const int j0    = (blk & 127) << 2;   // 4 owned h-units
  const int lane  = tid & 63;
  const int wv    = tid >> 6;           // 8 waves
  const int khalf = wv >> 2;            // K-half across wave pairs
  const int ntile = wv & 3;             // 4 N-tiles of 16 batch cols
  const int quad  = lane >> 4;
  const int mrow  = lane & 15;
  const int col   = ntile * 16 + mrow;  // batch column in C

  const float* __restrict__ Wih = dir ? p.WihB : p.WihF;
  const float* __restrict__ Whh = dir ? p.WhhB : p.WhhF;
  const float* bih = dir ? p.bihB : p.bihF;
  const float* bhh = dir ? p.bhhB : p.bhhF;

  // ---- one-time: weights -> register/AGPR A-fragments, split bf16 hi/lo ----
  // A layout: A[m=lane&15][k=quad*8+j]; row m -> gate g=m&3, unit jj=m>>2
  // => C lane regs 0..3 = 4 gates of unit `quad` for batch `col`. No transpose.
  bf16x8 aXhi[8], aXlo[8], aHhi[8], aHlo[8];
  const int grow = (mrow & 3) * HH + j0 + (mrow >> 2);
  #pragma unroll
  for (int s8 = 0; s8 < 8; ++s8) {
    const int kb = khalf * 256 + s8 * 32 + quad * 8;
    const float* wp = Wih + (size_t)grow * HH + kb;
    const float* wq = Whh + (size_t)grow * HH + kb;
    #pragma unroll
    for (int j = 0; j < 8; ++j) {
      float v = wp[j];
      __bf16 h = (__bf16)v;
      aXhi[s8][j] = h; aXlo[s8][j] = (__bf16)(v - (float)h);
      float u = wq[j];
      __bf16 g = (__bf16)u;
      aHhi[s8][j] = g; aHlo[s8][j] = (__bf16)(u - (float)g);
    }
  }
  float bias4[4];
  #pragma unroll
  for (int g = 0; g < 4; ++g)
    bias4[g] = bih[g * HH + j0 + quad] + bhh[g * HH + j0 + quad];

  float c_reg = 0.0f;
  u32* hT0   = p.hx + (size_t)dir * (2 * HH * BB);  // [buf][b][j] packed hi|lo<<16
  int* slots = p.bar;
  const int gb = dir * 128;

  __syncthreads();

  #pragma unroll 1
  for (int s = 0; s < LL; ++s) {
    const int t = dir ? (LL - 1 - s) : s;
    f32x4 acc = {0.f, 0.f, 0.f, 0.f};

    // ---------- stage x(t): emb gather -> split bf16 hi/lo in LDS ----------
    #pragma unroll 4
    for (int it = 0; it < 16; ++it) {
      int lin = (tid << 2) + (it << 11);
      int b = lin >> 9, k = lin & 511;
      int tok = p.tokens[t * BB + b];
      float4 v = make_float4(0.f, 0.f, 0.f, 0.f);
      if (tok >= 0) v = *(const float4*)(p.emb + (size_t)tok * HH + k);
      u16 h0, h1, h2, h3, l0, l1, l2, l3;
      split1(v.x, h0, l0); split1(v.y, h1, l1);
      split1(v.z, h2, l2); split1(v.w, h3, l3);
      u64 hp = (u64)h0 | ((u64)h1 << 16) | ((u64)h2 << 32) | ((u64)h3 << 48);
      u64 lp = (u64)l0 | ((u64)l1 << 16) | ((u64)l2 << 32) | ((u64)l3 << 48);
      *(u64*)&zhi[b * 520 + k] = hp;
      *(u64*)&zlo[b * 520 + k] = lp;
    }
    __syncthreads();

    // ---------- MFMA phase X (independent of the barrier below) ----------
    #pragma unroll
    for (int s8 = 0; s8 < 8; ++s8) {
      const int kk = khalf * 256 + s8 * 32 + quad * 8;
      bf16x8 bh = *(const bf16x8*)&zhi[col * 520 + kk];
      bf16x8 bl = *(const bf16x8*)&zlo[col * 520 + kk];
      acc = __builtin_amdgcn_mfma_f32_16x16x32_bf16(aXhi[s8], bh, acc, 0, 0, 0);
      acc = __builtin_amdgcn_mfma_f32_16x16x32_bf16(aXhi[s8], bl, acc, 0, 0, 0);
      acc = __builtin_amdgcn_mfma_f32_16x16x32_bf16(aXlo[s8], bh, acc, 0, 0, 0);
    }

    // ---------- wait-late: all 128 group blocks arrived step s ----------
    if (s) {
      for (;;) {
        int ok = 1;
        if (tid < 128)
          ok = (__hip_atomic_load(&slots[gb + tid], __ATOMIC_RELAXED,
                                  __HIP_MEMORY_SCOPE_AGENT) >= s);
        if (__syncthreads_and(ok)) break;
      }
      asm volatile("" ::: "memory");  // keep h loads below the poll
    }

    // ---------- stage h(s-1): relaxed 8B loads -> LDS (already split) ----------
    const u64* hbp = (const u64*)(hT0 + (size_t)(s & 1) * (HH * BB));
    #pragma unroll 8
    for (int it = 0; it < 32; ++it) {
      int idx = tid + (it << 9);              // u64 index, 16384 total
      u64 v = __hip_atomic_load(&hbp[idx], __ATOMIC_RELAXED, __HIP_MEMORY_SCOPE_AGENT);
      u32 u0 = (u32)v, u1 = (u32)(v >> 32);
      int b = idx >> 8, j = (idx & 255) << 1;
      *(u32*)&zhi[b * 520 + j] = (u0 & 0xffffu) | (u1 << 16);
      *(u32*)&zlo[b * 520 + j] = (u0 >> 16) | (u1 & 0xffff0000u);
    }
    __syncthreads();

    // ---------- MFMA phase H ----------
    #pragma unroll
    for (int s8 = 0; s8 < 8; ++s8) {
      const int kk = khalf * 256 + s8 * 32 + quad * 8;
      bf16x8 bh = *(const bf16x8*)&zhi[col * 520 + kk];
      bf16x8 bl = *(const bf16x8*)&zlo[col * 520 + kk];
      acc = __builtin_amdgcn_mfma_f32_16x16x32_bf16(aHhi[s8], bh, acc, 0, 0, 0);
      acc = __builtin_amdgcn_mfma_f32_16x16x32_bf16(aHhi[s8], bl, acc, 0, 0, 0);
      acc = __builtin_amdgcn_mfma_f32_16x16x32_bf16(aHlo[s8], bh, acc, 0, 0, 0);
    }

    // ---------- k-half reduce + gates (in-lane) ----------
    red[wv * 64 + lane] = acc;
    __syncthreads();
    if (wv < 4) {
      f32x4 o = red[(wv + 4) * 64 + lane];
      float g0 = acc[0] + o[0] + bias4[0];
      float g1 = acc[1] + o[1] + bias4[1];
      float g2 = acc[2] + o[2] + bias4[2];
      float g3 = acc[3] + o[3] + bias4[3];
      float ig = sigf(g0), fg = sigf(g1), gg = tanh2(g2), og = sigf(g3);
      float m  = p.mask[t * BB + col];
      float cu = fg * c_reg + ig * gg;
      float hu = og * tanh2(cu);
      c_reg = cu * m;
      hsh[quad * 64 + col] = hu * m;
    }
    __syncthreads();

    // ---------- wave0: publish h (relaxed SC1) + out; arrive ----------
    if (wv == 0) {
      float4 o4 = make_float4(hsh[lane], hsh[64 + lane], hsh[128 + lane], hsh[192 + lane]);
      // out: plain cached store (flushed at dispatch end)
      *(float4*)(p.out + ((size_t)(t * BB + lane)) * (2 * HH) + dir * HH + j0) = o4;
      // h: packed split-bf16, relaxed agent atomics (straight to L3)
      u16 h0, h1, h2, h3, l0, l1, l2, l3;
      split1(o4.x, h0, l0); split1(o4.y, h1, l1);
      split1(o4.z, h2, l2); split1(o4.w, h3, l3);
      u64 w0 = ((u64)h0 | ((u64)l0 << 16)) | (((u64)h1 | ((u64)l1 << 16)) << 32);
      u64 w1 = ((u64)h2 | ((u64)l2 << 16)) | (((u64)h3 | ((u64)l3 << 16)) << 32);
      u64* dst = (u64*)(hT0 + (size_t)((s & 1) ^ 1) * (HH * BB)) + ((lane * 512 + j0) >> 1);
      __hip_atomic_store(&dst[0], w0, __ATOMIC_RELAXED, __HIP_MEMORY_SCOPE_AGENT);
      __hip_atomic_store(&dst[1], w1, __ATOMIC_RELAXED, __HIP_MEMORY_SCOPE_AGENT);
      asm volatile("s_waitcnt vmcnt(0)" ::: "memory");  // h at L3 before flag
      if (tid == 0)
        __hip_atomic_store(&slots[gb + (blk & 127)], s + 1, __ATOMIC_RELAXED,
                           __HIP_MEMORY_SCOPE_AGENT);
    }
    // other waves run ahead into next step's x-staging (disjoint LDS vs hsh)
  }
}

extern "C" void kernel_launch(void* const* d_in, const int* in_sizes, int n_in,
                              void* d_out, int out_size, void* d_ws, size_t ws_size,
                              hipStream_t stream) {
  (void)in_sizes; (void)n_in; (void)out_size; (void)ws_size;
  Params prm;
  prm.tokens = (const int*)d_in[0];
  prm.mask   = (const float*)d_in[1];
  prm.emb    = (const float*)d_in[2];
  prm.WihF   = (const float*)d_in[3];
  prm.WhhF   = (const float*)d_in[4];
  prm.bihF   = (const float*)d_in[5];
  prm.bhhF   = (const float*)d_in[6];
  prm.WihB   = (const float*)d_in[7];
  prm.WhhB   = (const float*)d_in[8];
  prm.bihB   = (const float*)d_in[9];
  prm.bhhB   = (const float*)d_in[10];
  prm.out    = (float*)d_out;
  // ws: [0,512K) h exchange [dir][buf][b][j] u32 (bf16 hi|lo); [512K,+4K) slots
  prm.hx  = (u32*)d_ws;
  prm.bar = (int*)((char*)d_ws + 524288);

  hipMemsetAsync(d_ws, 0, 528384, stream);

  void* args[] = {(void*)&prm};
  hipLaunchCooperativeKernel((const void*)lstm_mfma, dim3(NBLK), dim3(NTHR), args, 0, stream);
}